// Round 17
// baseline (6204.100 us; speedup 1.0000x reference)
//
#include <hip/hip_runtime.h>
#include <hip/hip_bf16.h>
#include <hip/hip_cooperative_groups.h>
#include <cstdint>
#include <cstring>

// Predictive-coding network inference, 20 relaxation steps.
// bf16 MFMA GEMMs (fp32 accum), fp32 master states + ping-pong bf16 shadows.
// R4:  G-terms fused into update GEMMs (L pre-scaled by -gamma).
// R6:  XCD-aware block->tile mapping (contiguous row-tile bands per XCD).
// R13: eps4 path eliminated algebraically (M4G = W4W4^T - gamma*L3, C4).
// R14: phase-1 epilogue reads bf16 shadows instead of fp32 masters.
// R16: all 40 step-dispatches merged into ONE cooperative persistent kernel
//      (grid.sync between phases); falls back to 40 dispatches if coop launch
//      is unavailable. Math identical either way (bit-identical output).

#define LRC 0.1f

namespace cg = cooperative_groups;

typedef unsigned short u16;
typedef unsigned int u32;
typedef __attribute__((ext_vector_type(4))) float f32x4;
typedef __attribute__((ext_vector_type(8))) __bf16 bf16x8;

__device__ __forceinline__ u16 f2b(float v) {
  __hip_bfloat16 h = __float2bfloat16(v);
  union { __hip_bfloat16 h; u16 u; } c; c.h = h; return c.u;
}
__device__ __forceinline__ float b2f(u16 u) {
  union { u16 u; __hip_bfloat16 h; } c; c.u = u; return __bfloat162float(c.h);
}
__device__ __forceinline__ float sigf(float x) { return 1.0f / (1.0f + expf(-x)); }

__device__ __forceinline__ void gll16(const void* g, void* l) {
  __builtin_amdgcn_global_load_lds((const __attribute__((address_space(1))) u32*)g,
                                   (__attribute__((address_space(3))) u32*)l,
                                   16, 0, 0);
}

struct GemmDesc {
  const u16* A; const u16* Bt;       // first GEMM (eps@W^T or forward)
  const u16* A2; const u16* Bt2;     // optional second GEMM (x@(-gamma L)^T)
  const float* bias; const float* master; const float* pred; const float* aux;
  const u16* eprev;
  float* outF; u16* outB;
  int lda, ldb, lda2, ldb2, K, K2, N, tnl, nblocks, epi;
};
struct Descs { GemmDesc d[6]; int nd; };
struct AllDesc { GemmDesc ph1[2][2]; GemmDesc ph2[2][3]; };

// epi: 1 = bf16( sigmoid(acc+bias[col]) - b2f(eprev[idx]) )   (e2, e3)
//      2 = fp32 sigmoid(acc+bias[col])                        (x1_pred)
//      3 = x1 update: eps = pred[idx]-v
//      4 = x2 update: eps = b2f(eprev[idx])
//      6 = x3 update: eps = b2f(eprev[idx]), grad-term = acc + pred[idx] (C4)
__device__ void do_gemm(const GemmDesc* __restrict__ dd, int nd, int bid, int tid) {
  int base = 0, di = 0;
  while (di + 1 < nd && bid >= base + dd[di].nblocks) { base += dd[di].nblocks; ++di; }
  const GemmDesc& d = dd[di];
  int t = bid - base;

  // K-split LDS: [2 subtiles][128 rows][32 cols] u16 per operand (16KB each)
  static __shared__ u16 ldsA[8192];
  static __shared__ u16 ldsB[8192];

  int w = tid >> 6, l = tid & 63;
  int wm = w & 1, wn = w >> 1;
  int lrow = l & 15, kgrp = l >> 4;

  // XCD-aware mapping: hw assigns blocks round-robin to XCDs (bid%8); for a
  // persistent block this is stable. Each XCD owns a contiguous band of
  // row-tiles so column-tiles sharing an A-panel hit the same per-XCD L2.
  int tnl = d.tnl;
  int j = t >> 3;
  int tm = (t & 7) * (d.nblocks >> (3 + tnl)) + (j >> tnl);
  int tnn = j & ((1 << tnl) - 1);
  int m0 = tm * 128, n0 = tnn * 128;

  f32x4 zero = {0.f, 0.f, 0.f, 0.f};
  f32x4 acc[4][4];
  #pragma unroll
  for (int a = 0; a < 4; ++a)
    #pragma unroll
    for (int b = 0; b < 4; ++b) acc[a][b] = zero;

  int srow = l >> 2;              // staging row within 16-row chunk
  int scol = (l & 3) * 8;         // staging col (u16) within 32-col subtile

  auto run = [&](const u16* A, int lda, const u16* Bt, int ldb, int K) {
    for (int k0 = 0; k0 < K;) {
      int nsub = (K - k0 >= 64) ? 2 : 1;
      for (int i = 0; i < 2 * nsub; ++i) {
        int c = i * 4 + w;                     // chunk id in [0, 8*nsub)
        int ks = c >> 3, rb = c & 7;
        int row = rb * 16 + srow;
        int col = k0 + ks * 32 + scol;
        gll16(A  + (size_t)(m0 + row) * lda + col, &ldsA[c * 512]);
        gll16(Bt + (size_t)(n0 + row) * ldb + col, &ldsB[c * 512]);
      }
      __syncthreads();
      for (int ks = 0; ks < nsub; ++ks) {
        bf16x8 af[4], bfr[4];
        #pragma unroll
        for (int mi = 0; mi < 4; ++mi)
          af[mi] = *(const bf16x8*)&ldsA[ks * 4096 + (wm * 64 + mi * 16 + lrow) * 32 + kgrp * 8];
        #pragma unroll
        for (int ni = 0; ni < 4; ++ni)
          bfr[ni] = *(const bf16x8*)&ldsB[ks * 4096 + (wn * 64 + ni * 16 + lrow) * 32 + kgrp * 8];
        #pragma unroll
        for (int mi = 0; mi < 4; ++mi)
          #pragma unroll
          for (int ni = 0; ni < 4; ++ni)
            acc[mi][ni] = __builtin_amdgcn_mfma_f32_16x16x32_bf16(af[mi], bfr[ni], acc[mi][ni], 0, 0, 0);
      }
      __syncthreads();
      k0 += nsub * 32;
    }
  };

  run(d.A, d.lda, d.Bt, d.ldb, d.K);
  if (d.K2 > 0) run(d.A2, d.lda2, d.Bt2, d.ldb2, d.K2);

  int epi = d.epi;
  #pragma unroll
  for (int mi = 0; mi < 4; ++mi) {
    #pragma unroll
    for (int ni = 0; ni < 4; ++ni) {
      #pragma unroll
      for (int j2 = 0; j2 < 4; ++j2) {
        int row = m0 + wm * 64 + mi * 16 + kgrp * 4 + j2;
        int col = n0 + wn * 64 + ni * 16 + lrow;
        size_t idx = (size_t)row * d.N + col;
        float a = acc[mi][ni][j2];
        if (epi == 1) {
          float s = sigf(a + d.bias[col]);
          d.outB[idx] = f2b(s - b2f(d.eprev[idx]));
        } else if (epi == 2) {
          d.outF[idx] = sigf(a + d.bias[col]);
        } else if (epi == 3) {
          float v = d.outF[idx];
          float nv = v + LRC * (d.pred[idx] - v) - LRC * a;
          d.outF[idx] = nv; d.outB[idx] = f2b(nv);
        } else if (epi == 4) {
          float v = d.outF[idx];
          float nv = v + LRC * b2f(d.eprev[idx]) - LRC * a;
          d.outF[idx] = nv; d.outB[idx] = f2b(nv);
        } else {  // 6: x3 update, constant C4 added to grad term
          float v = d.outF[idx];
          float nv = v + LRC * b2f(d.eprev[idx]) - LRC * (a + d.pred[idx]);
          d.outF[idx] = nv; d.outB[idx] = f2b(nv);
        }
      }
    }
  }
}

__global__ __launch_bounds__(256) void k_gemm_multi(Descs P) {
  do_gemm(P.d, P.nd, blockIdx.x, threadIdx.x);
}

// Persistent cooperative kernel: 20 steps, grid.sync between phases.
// grid = 768 blocks (3/CU co-resident: LDS 32KB -> 5/CU, launch_bounds caps VGPR).
__global__ __launch_bounds__(256, 3) void k_steps(AllDesc P) {
  cg::grid_group g = cg::this_grid();
  int tid = threadIdx.x;
  for (int s = 0; s < 20; ++s) {
    int p = s & 1;
    for (int job = blockIdx.x; job < 640; job += gridDim.x)
      do_gemm(P.ph1[p], 2, job, tid);
    g.sync();
    for (int job = blockIdx.x; job < 768; job += gridDim.x)
      do_gemm(P.ph2[p], 3, job, tid);
    g.sync();
  }
}

__global__ void k_state_init(const float* __restrict__ src, float* __restrict__ dstF,
                             u16* __restrict__ dstB, int n) {
  int i = blockIdx.x * 256 + threadIdx.x;
  if (i < n) { float v = src[i]; dstF[i] = v; dstB[i] = f2b(v); }
}
__global__ void k_transpose_scale(const float* __restrict__ src, u16* __restrict__ dst,
                                  int R, int C, float scale) {
  int i = blockIdx.x * 256 + threadIdx.x;
  if (i < R * C) { int r = i / C, c = i - r * C; dst[c * R + r] = f2b(scale * src[i]); }
}
__global__ void k_conv_bf(const float* __restrict__ src, u16* __restrict__ dst, int n) {
  int i = blockIdx.x * 256 + threadIdx.x;
  if (i < n) dst[i] = f2b(src[i]);
}
// M4G[n][k] = dot(W4 row n, W4 row k) - 0.1*L3[k][n]   (Bt layout for x3 GEMM)
__global__ void k_m4g(const float* __restrict__ W4, const float* __restrict__ L3,
                      u16* __restrict__ dst) {
  int i = blockIdx.x * 256 + threadIdx.x;
  if (i < 256 * 256) {
    int n = i >> 8, k = i & 255;
    float s = 0.f;
    #pragma unroll
    for (int jj = 0; jj < 10; ++jj) s = fmaf(W4[n * 10 + jj], W4[k * 10 + jj], s);
    dst[i] = f2b(s - 0.1f * L3[k * 256 + n]);
  }
}
// C4[m][n] = sum_j (b4[j] - x4_0[m][j]) * W4[n][j]   (fp32, step-invariant)
__global__ void k_c4(const float* __restrict__ W4, const float* __restrict__ b4,
                     const float* __restrict__ x40, float* __restrict__ dst) {
  int i = blockIdx.x * 256 + threadIdx.x;
  if (i < 8192 * 256) {
    int m = i >> 8, n = i & 255;
    float s = 0.f;
    #pragma unroll
    for (int jj = 0; jj < 10; ++jj) s = fmaf(b4[jj] - x40[m * 10 + jj], W4[n * 10 + jj], s);
    dst[i] = s;
  }
}
// x split into [hi(784) pad16 | lo(784) pad16]  -> [8192][1600]
__global__ void k_xsplit(const float* __restrict__ x, u16* __restrict__ dst) {
  int i = blockIdx.x * 256 + threadIdx.x;
  if (i < 8192 * 1600) {
    int m = i / 1600, c = i - m * 1600;
    u16 o = 0;
    if (c < 784) o = f2b(x[m * 784 + c]);
    else if (c >= 800 && c < 1584) {
      float v = x[m * 784 + (c - 800)];
      float h = b2f(f2b(v));
      o = f2b(v - h);
    }
    dst[i] = o;
  }
}
// W1 companion: both halves hold bf16(W1^T), so (hi+lo) @ W1b == x @ bf16(W1)
__global__ void k_w1c(const float* __restrict__ W1, u16* __restrict__ dst) {
  int i = blockIdx.x * 256 + threadIdx.x;
  if (i < 256 * 1600) {
    int n = i / 1600, c = i - n * 1600;
    u16 o = 0;
    if (c < 784) o = f2b(W1[c * 256 + n]);
    else if (c >= 800 && c < 1584) o = f2b(W1[(c - 800) * 256 + n]);
    dst[i] = o;
  }
}
__global__ void k_final(const float* __restrict__ X3, const float* __restrict__ W4,
                        const float* __restrict__ b4, float* __restrict__ out) {
  int i = blockIdx.x * 256 + threadIdx.x;
  if (i < 8192 * 10) {
    int m = i / 10, n = i - m * 10;
    const float* xr = X3 + (size_t)m * 256;
    float acc = 0.f;
    #pragma unroll 4
    for (int k = 0; k < 256; ++k) acc = fmaf(xr[k], W4[k * 10 + n], acc);
    out[i] = acc + b4[n];
  }
}

extern "C" void kernel_launch(void* const* d_in, const int* in_sizes, int n_in,
                              void* d_out, int out_size, void* d_ws, size_t ws_size,
                              hipStream_t stream) {
  const float* x    = (const float*)d_in[0];
  const float* x1_0 = (const float*)d_in[1];
  const float* x2_0 = (const float*)d_in[2];
  const float* x3_0 = (const float*)d_in[3];
  const float* x4_0 = (const float*)d_in[4];
  const float* W1 = (const float*)d_in[5];
  const float* W2 = (const float*)d_in[6];
  const float* W3 = (const float*)d_in[7];
  const float* W4 = (const float*)d_in[8];
  const float* b1 = (const float*)d_in[9];
  const float* b2 = (const float*)d_in[10];
  const float* b3 = (const float*)d_in[11];
  const float* b4 = (const float*)d_in[12];
  const float* L1 = (const float*)d_in[13];
  const float* L2 = (const float*)d_in[14];
  const float* L3 = (const float*)d_in[15];

  if (ws_size < 143687680u) return;
  char* ws = (char*)d_ws;
  float* X1f   = (float*)(ws + 0);
  float* X2f   = (float*)(ws + 8388608);
  float* X3f   = (float*)(ws + 41943040);
  u16*   X1b[2]= { (u16*)(ws + 50331648), (u16*)(ws + 54525952) };
  u16*   X2b[2]= { (u16*)(ws + 58720256), (u16*)(ws + 75497472) };
  u16*   X3b[2]= { (u16*)(ws + 92274688), (u16*)(ws + 96468992) };
  float* P1    = (float*)(ws + 100663296);
  u16*   E2    = (u16*)(ws + 109051904);
  u16*   E3    = (u16*)(ws + 125829120);
  float* C4    = (float*)(ws + 130023424);        // 8MB, ends 138412032
  u16*   XS    = (u16*)(ws + 109051904);  // aliases E2/E3/C4 (prologue-only use)
  u16*   W2t   = (u16*)(ws + 138412032);
  u16*   W3t   = (u16*)(ws + 138936320);
  u16*   L1t   = (u16*)(ws + 139460608);
  u16*   L2t   = (u16*)(ws + 139591680);
  u16*   M4G   = (u16*)(ws + 141688832);
  u16*   W2b   = (u16*)(ws + 141819904);
  u16*   W3b   = (u16*)(ws + 142344192);
  u16*   W1c   = (u16*)(ws + 142868480);          // ends 143687680

  dim3 blk(256);
  auto G = [](int n) { return dim3((unsigned)((n + 255) / 256)); };

  // ---- prologue ----
  k_state_init<<<G(8192*256),  blk, 0, stream>>>(x1_0, X1f, X1b[0], 8192*256);
  k_state_init<<<G(8192*1024), blk, 0, stream>>>(x2_0, X2f, X2b[0], 8192*1024);
  k_state_init<<<G(8192*256),  blk, 0, stream>>>(x3_0, X3f, X3b[0], 8192*256);
  k_transpose_scale<<<G(256*1024),  blk, 0, stream>>>(W2, W2t, 256, 1024, 1.0f);
  k_transpose_scale<<<G(1024*256),  blk, 0, stream>>>(W3, W3t, 1024, 256, 1.0f);
  k_transpose_scale<<<G(256*256),   blk, 0, stream>>>(L1, L1t, 256, 256, -0.1f);
  k_transpose_scale<<<G(1024*1024), blk, 0, stream>>>(L2, L2t, 1024, 1024, -0.1f);
  k_conv_bf<<<G(256*1024), blk, 0, stream>>>(W2, W2b, 256*1024);
  k_conv_bf<<<G(1024*256), blk, 0, stream>>>(W3, W3b, 1024*256);
  k_m4g<<<G(256*256), blk, 0, stream>>>(W4, L3, M4G);
  k_xsplit<<<G(8192*1600), blk, 0, stream>>>(x, XS);
  k_w1c<<<G(256*1600), blk, 0, stream>>>(W1, W1c);

  auto mkg = [](const u16* A, const u16* Bt, int lda, int ldb, int K, int N,
                int tnl, int nb, int epi) {
    GemmDesc g; memset(&g, 0, sizeof(g));
    g.A = A; g.Bt = Bt; g.lda = lda; g.ldb = ldb; g.K = K; g.N = N;
    g.tnl = tnl; g.nblocks = nb; g.epi = epi;
    return g;
  };

  {  // x1_pred = sigmoid(x @ W1 + b1), via hi/lo K-concat (K=1600)
    Descs pp; memset(&pp, 0, sizeof(pp)); pp.nd = 1;
    pp.d[0] = mkg(XS, W1c, 1600, 1600, 1600, 256, 1, 128, 2);
    pp.d[0].bias = b1; pp.d[0].outF = P1;
    k_gemm_multi<<<dim3(128), blk, 0, stream>>>(pp);
  }
  // C4 AFTER x1_pred gemm (C4 aliases XS region)
  k_c4<<<G(8192*256), blk, 0, stream>>>(W4, b4, x4_0, C4);

  // ---- build both-parity descriptor tables ----
  AllDesc AD; memset(&AD, 0, sizeof(AD));
  for (int p = 0; p < 2; ++p) {
    int q = p ^ 1;
    // phase 1: e3 (K=1024) heavy-first, e2 -- epilogues read bf16 shadows
    AD.ph1[p][0] = mkg(X2b[p], W3t, 1024, 1024, 1024, 256, 1, 128, 1);
    AD.ph1[p][0].bias = b3; AD.ph1[p][0].eprev = X3b[p]; AD.ph1[p][0].outB = E3;
    AD.ph1[p][1] = mkg(X1b[p], W2t, 256, 256, 256, 1024, 3, 512, 1);
    AD.ph1[p][1].bias = b2; AD.ph1[p][1].eprev = X2b[p]; AD.ph1[p][1].outB = E2;
    // phase 2: fused updates
    AD.ph2[p][0] = mkg(E3, W3b, 256, 256, 256, 1024, 3, 512, 4);
    AD.ph2[p][0].A2 = X2b[p]; AD.ph2[p][0].Bt2 = L2t; AD.ph2[p][0].lda2 = 1024;
    AD.ph2[p][0].ldb2 = 1024; AD.ph2[p][0].K2 = 1024;
    AD.ph2[p][0].eprev = E2; AD.ph2[p][0].outF = X2f; AD.ph2[p][0].outB = X2b[q];
    AD.ph2[p][1] = mkg(E2, W2b, 1024, 1024, 1024, 256, 1, 128, 3);
    AD.ph2[p][1].A2 = X1b[p]; AD.ph2[p][1].Bt2 = L1t; AD.ph2[p][1].lda2 = 256;
    AD.ph2[p][1].ldb2 = 256; AD.ph2[p][1].K2 = 256;
    AD.ph2[p][1].pred = P1; AD.ph2[p][1].outF = X1f; AD.ph2[p][1].outB = X1b[q];
    AD.ph2[p][2] = mkg(X3b[p], M4G, 256, 256, 256, 256, 1, 128, 6);
    AD.ph2[p][2].eprev = E3; AD.ph2[p][2].pred = C4;
    AD.ph2[p][2].outF = X3f; AD.ph2[p][2].outB = X3b[q];
  }

  // ---- 20 steps: one cooperative persistent kernel (grid.sync between
  // phases); identical-math fallback to 40 dispatches if coop unavailable ----
  void* kargs[] = { (void*)&AD };
  hipError_t ce = hipLaunchCooperativeKernel((const void*)k_steps, dim3(768), blk,
                                             kargs, 0, stream);
  if (ce != hipSuccess) {
    (void)hipGetLastError();   // clear error state
    for (int s = 0; s < 20; ++s) {
      int p = s & 1;
      Descs d1; memset(&d1, 0, sizeof(d1)); d1.nd = 2;
      d1.d[0] = AD.ph1[p][0]; d1.d[1] = AD.ph1[p][1];
      k_gemm_multi<<<dim3(640), blk, 0, stream>>>(d1);
      Descs d2; memset(&d2, 0, sizeof(d2)); d2.nd = 3;
      d2.d[0] = AD.ph2[p][0]; d2.d[1] = AD.ph2[p][1]; d2.d[2] = AD.ph2[p][2];
      k_gemm_multi<<<dim3(768), blk, 0, stream>>>(d2);
    }
  }

  k_final<<<G(81920), blk, 0, stream>>>(X3f, W4, b4, (float*)d_out);
}

// Round 21
// 2331.416 us; speedup vs baseline: 2.6611x; 2.6611x over previous
//
#include <hip/hip_runtime.h>
#include <hip/hip_bf16.h>
#include <cstdint>
#include <cstring>

// Predictive-coding network inference, 20 relaxation steps.
// bf16 MFMA GEMMs (fp32 accum), fp32 master states + ping-pong bf16 shadows.
// R4:  G-terms fused into update GEMMs (L pre-scaled by -gamma).
// R6:  XCD-aware block->tile mapping (contiguous row-tile bands per XCD).
// R13: eps4 path eliminated algebraically (M4G = W4W4^T - gamma*L3, C4).
// R14: phase-1 epilogue reads bf16 shadows instead of fp32 masters.
// R18: FINAL -- revert R15 (register-A: VGPR 160, uncoalesced) and R16/R17
//      (cooperative grid.sync costs ~100us/sync on 8-XCD MI355X). This is the
//      measured-best configuration (2334 us).

#define LRC 0.1f

typedef unsigned short u16;
typedef unsigned int u32;
typedef __attribute__((ext_vector_type(4))) float f32x4;
typedef __attribute__((ext_vector_type(8))) __bf16 bf16x8;

__device__ __forceinline__ u16 f2b(float v) {
  __hip_bfloat16 h = __float2bfloat16(v);
  union { __hip_bfloat16 h; u16 u; } c; c.h = h; return c.u;
}
__device__ __forceinline__ float b2f(u16 u) {
  union { u16 u; __hip_bfloat16 h; } c; c.u = u; return __bfloat162float(c.h);
}
__device__ __forceinline__ float sigf(float x) { return 1.0f / (1.0f + expf(-x)); }

__device__ __forceinline__ void gll16(const void* g, void* l) {
  __builtin_amdgcn_global_load_lds((const __attribute__((address_space(1))) u32*)g,
                                   (__attribute__((address_space(3))) u32*)l,
                                   16, 0, 0);
}

struct GemmDesc {
  const u16* A; const u16* Bt;       // first GEMM (eps@W^T or forward)
  const u16* A2; const u16* Bt2;     // optional second GEMM (x@(-gamma L)^T)
  const float* bias; const float* master; const float* pred; const float* aux;
  const u16* eprev;
  float* outF; u16* outB;
  int lda, ldb, lda2, ldb2, K, K2, N, tnl, nblocks, epi;
};
struct Descs { GemmDesc d[6]; int nd; };

// epi: 1 = bf16( sigmoid(acc+bias[col]) - b2f(eprev[idx]) )   (e2, e3)
//      2 = fp32 sigmoid(acc+bias[col])                        (x1_pred)
//      3 = x1 update: eps = pred[idx]-v
//      4 = x2 update: eps = b2f(eprev[idx])
//      6 = x3 update: eps = b2f(eprev[idx]), grad-term = acc + pred[idx] (C4)
__global__ __launch_bounds__(256) void k_gemm_multi(Descs P) {
  int bid = blockIdx.x;
  int base = 0, di = 0;
  while (di + 1 < P.nd && bid >= base + P.d[di].nblocks) { base += P.d[di].nblocks; ++di; }
  const GemmDesc& d = P.d[di];
  int t = bid - base;
  int tid = threadIdx.x;

  // K-split LDS: [2 subtiles][128 rows][32 cols] u16 per operand (16KB each)
  __shared__ u16 ldsA[8192];
  __shared__ u16 ldsB[8192];

  int w = tid >> 6, l = tid & 63;
  int wm = w & 1, wn = w >> 1;
  int lrow = l & 15, kgrp = l >> 4;

  // XCD-aware mapping: hw assigns blockIdx round-robin to XCDs (bid%8).
  // Give each XCD a contiguous band of row-tiles so the column-tiles sharing
  // an A-panel hit the same (non-coherent) per-XCD L2.
  // Requires nblocks % 8 == 0 and base % 8 == 0 (all descs satisfy this).
  int tnl = d.tnl;
  int j = t >> 3;
  int tm = (t & 7) * (d.nblocks >> (3 + tnl)) + (j >> tnl);
  int tnn = j & ((1 << tnl) - 1);
  int m0 = tm * 128, n0 = tnn * 128;

  f32x4 zero = {0.f, 0.f, 0.f, 0.f};
  f32x4 acc[4][4];
  #pragma unroll
  for (int a = 0; a < 4; ++a)
    #pragma unroll
    for (int b = 0; b < 4; ++b) acc[a][b] = zero;

  int srow = l >> 2;              // staging row within 16-row chunk
  int scol = (l & 3) * 8;         // staging col (u16) within 32-col subtile

  auto run = [&](const u16* A, int lda, const u16* Bt, int ldb, int K) {
    for (int k0 = 0; k0 < K;) {
      int nsub = (K - k0 >= 64) ? 2 : 1;
      for (int i = 0; i < 2 * nsub; ++i) {
        int c = i * 4 + w;                     // chunk id in [0, 8*nsub)
        int ks = c >> 3, rb = c & 7;
        int row = rb * 16 + srow;
        int col = k0 + ks * 32 + scol;
        gll16(A  + (size_t)(m0 + row) * lda + col, &ldsA[c * 512]);
        gll16(Bt + (size_t)(n0 + row) * ldb + col, &ldsB[c * 512]);
      }
      __syncthreads();
      for (int ks = 0; ks < nsub; ++ks) {
        bf16x8 af[4], bfr[4];
        #pragma unroll
        for (int mi = 0; mi < 4; ++mi)
          af[mi] = *(const bf16x8*)&ldsA[ks * 4096 + (wm * 64 + mi * 16 + lrow) * 32 + kgrp * 8];
        #pragma unroll
        for (int ni = 0; ni < 4; ++ni)
          bfr[ni] = *(const bf16x8*)&ldsB[ks * 4096 + (wn * 64 + ni * 16 + lrow) * 32 + kgrp * 8];
        #pragma unroll
        for (int mi = 0; mi < 4; ++mi)
          #pragma unroll
          for (int ni = 0; ni < 4; ++ni)
            acc[mi][ni] = __builtin_amdgcn_mfma_f32_16x16x32_bf16(af[mi], bfr[ni], acc[mi][ni], 0, 0, 0);
      }
      __syncthreads();
      k0 += nsub * 32;
    }
  };

  run(d.A, d.lda, d.Bt, d.ldb, d.K);
  if (d.K2 > 0) run(d.A2, d.lda2, d.Bt2, d.ldb2, d.K2);

  int epi = d.epi;
  #pragma unroll
  for (int mi = 0; mi < 4; ++mi) {
    #pragma unroll
    for (int ni = 0; ni < 4; ++ni) {
      #pragma unroll
      for (int j2 = 0; j2 < 4; ++j2) {
        int row = m0 + wm * 64 + mi * 16 + kgrp * 4 + j2;
        int col = n0 + wn * 64 + ni * 16 + lrow;
        size_t idx = (size_t)row * d.N + col;
        float a = acc[mi][ni][j2];
        if (epi == 1) {
          float s = sigf(a + d.bias[col]);
          d.outB[idx] = f2b(s - b2f(d.eprev[idx]));
        } else if (epi == 2) {
          d.outF[idx] = sigf(a + d.bias[col]);
        } else if (epi == 3) {
          float v = d.outF[idx];
          float nv = v + LRC * (d.pred[idx] - v) - LRC * a;
          d.outF[idx] = nv; d.outB[idx] = f2b(nv);
        } else if (epi == 4) {
          float v = d.outF[idx];
          float nv = v + LRC * b2f(d.eprev[idx]) - LRC * a;
          d.outF[idx] = nv; d.outB[idx] = f2b(nv);
        } else {  // 6: x3 update, constant C4 added to grad term
          float v = d.outF[idx];
          float nv = v + LRC * b2f(d.eprev[idx]) - LRC * (a + d.pred[idx]);
          d.outF[idx] = nv; d.outB[idx] = f2b(nv);
        }
      }
    }
  }
}

__global__ void k_state_init(const float* __restrict__ src, float* __restrict__ dstF,
                             u16* __restrict__ dstB, int n) {
  int i = blockIdx.x * 256 + threadIdx.x;
  if (i < n) { float v = src[i]; dstF[i] = v; dstB[i] = f2b(v); }
}
__global__ void k_transpose_scale(const float* __restrict__ src, u16* __restrict__ dst,
                                  int R, int C, float scale) {
  int i = blockIdx.x * 256 + threadIdx.x;
  if (i < R * C) { int r = i / C, c = i - r * C; dst[c * R + r] = f2b(scale * src[i]); }
}
__global__ void k_conv_bf(const float* __restrict__ src, u16* __restrict__ dst, int n) {
  int i = blockIdx.x * 256 + threadIdx.x;
  if (i < n) dst[i] = f2b(src[i]);
}
// M4G[n][k] = dot(W4 row n, W4 row k) - 0.1*L3[k][n]   (Bt layout for x3 GEMM)
__global__ void k_m4g(const float* __restrict__ W4, const float* __restrict__ L3,
                      u16* __restrict__ dst) {
  int i = blockIdx.x * 256 + threadIdx.x;
  if (i < 256 * 256) {
    int n = i >> 8, k = i & 255;
    float s = 0.f;
    #pragma unroll
    for (int jj = 0; jj < 10; ++jj) s = fmaf(W4[n * 10 + jj], W4[k * 10 + jj], s);
    dst[i] = f2b(s - 0.1f * L3[k * 256 + n]);
  }
}
// C4[m][n] = sum_j (b4[j] - x4_0[m][j]) * W4[n][j]   (fp32, step-invariant)
__global__ void k_c4(const float* __restrict__ W4, const float* __restrict__ b4,
                     const float* __restrict__ x40, float* __restrict__ dst) {
  int i = blockIdx.x * 256 + threadIdx.x;
  if (i < 8192 * 256) {
    int m = i >> 8, n = i & 255;
    float s = 0.f;
    #pragma unroll
    for (int jj = 0; jj < 10; ++jj) s = fmaf(b4[jj] - x40[m * 10 + jj], W4[n * 10 + jj], s);
    dst[i] = s;
  }
}
// x split into [hi(784) pad16 | lo(784) pad16]  -> [8192][1600]
__global__ void k_xsplit(const float* __restrict__ x, u16* __restrict__ dst) {
  int i = blockIdx.x * 256 + threadIdx.x;
  if (i < 8192 * 1600) {
    int m = i / 1600, c = i - m * 1600;
    u16 o = 0;
    if (c < 784) o = f2b(x[m * 784 + c]);
    else if (c >= 800 && c < 1584) {
      float v = x[m * 784 + (c - 800)];
      float h = b2f(f2b(v));
      o = f2b(v - h);
    }
    dst[i] = o;
  }
}
// W1 companion: both halves hold bf16(W1^T), so (hi+lo) @ W1b == x @ bf16(W1)
__global__ void k_w1c(const float* __restrict__ W1, u16* __restrict__ dst) {
  int i = blockIdx.x * 256 + threadIdx.x;
  if (i < 256 * 1600) {
    int n = i / 1600, c = i - n * 1600;
    u16 o = 0;
    if (c < 784) o = f2b(W1[c * 256 + n]);
    else if (c >= 800 && c < 1584) o = f2b(W1[(c - 800) * 256 + n]);
    dst[i] = o;
  }
}
__global__ void k_final(const float* __restrict__ X3, const float* __restrict__ W4,
                        const float* __restrict__ b4, float* __restrict__ out) {
  int i = blockIdx.x * 256 + threadIdx.x;
  if (i < 8192 * 10) {
    int m = i / 10, n = i - m * 10;
    const float* xr = X3 + (size_t)m * 256;
    float acc = 0.f;
    #pragma unroll 4
    for (int k = 0; k < 256; ++k) acc = fmaf(xr[k], W4[k * 10 + n], acc);
    out[i] = acc + b4[n];
  }
}

extern "C" void kernel_launch(void* const* d_in, const int* in_sizes, int n_in,
                              void* d_out, int out_size, void* d_ws, size_t ws_size,
                              hipStream_t stream) {
  const float* x    = (const float*)d_in[0];
  const float* x1_0 = (const float*)d_in[1];
  const float* x2_0 = (const float*)d_in[2];
  const float* x3_0 = (const float*)d_in[3];
  const float* x4_0 = (const float*)d_in[4];
  const float* W1 = (const float*)d_in[5];
  const float* W2 = (const float*)d_in[6];
  const float* W3 = (const float*)d_in[7];
  const float* W4 = (const float*)d_in[8];
  const float* b1 = (const float*)d_in[9];
  const float* b2 = (const float*)d_in[10];
  const float* b3 = (const float*)d_in[11];
  const float* b4 = (const float*)d_in[12];
  const float* L1 = (const float*)d_in[13];
  const float* L2 = (const float*)d_in[14];
  const float* L3 = (const float*)d_in[15];

  if (ws_size < 143687680u) return;
  char* ws = (char*)d_ws;
  float* X1f   = (float*)(ws + 0);
  float* X2f   = (float*)(ws + 8388608);
  float* X3f   = (float*)(ws + 41943040);
  u16*   X1b[2]= { (u16*)(ws + 50331648), (u16*)(ws + 54525952) };
  u16*   X2b[2]= { (u16*)(ws + 58720256), (u16*)(ws + 75497472) };
  u16*   X3b[2]= { (u16*)(ws + 92274688), (u16*)(ws + 96468992) };
  float* P1    = (float*)(ws + 100663296);
  u16*   E2    = (u16*)(ws + 109051904);
  u16*   E3    = (u16*)(ws + 125829120);
  float* C4    = (float*)(ws + 130023424);        // 8MB, ends 138412032
  u16*   XS    = (u16*)(ws + 109051904);  // aliases E2/E3/C4 (prologue-only use)
  u16*   W2t   = (u16*)(ws + 138412032);
  u16*   W3t   = (u16*)(ws + 138936320);
  u16*   L1t   = (u16*)(ws + 139460608);
  u16*   L2t   = (u16*)(ws + 139591680);
  u16*   M4G   = (u16*)(ws + 141688832);
  u16*   W2b   = (u16*)(ws + 141819904);
  u16*   W3b   = (u16*)(ws + 142344192);
  u16*   W1c   = (u16*)(ws + 142868480);          // ends 143687680

  dim3 blk(256);
  auto G = [](int n) { return dim3((unsigned)((n + 255) / 256)); };

  // ---- prologue ----
  k_state_init<<<G(8192*256),  blk, 0, stream>>>(x1_0, X1f, X1b[0], 8192*256);
  k_state_init<<<G(8192*1024), blk, 0, stream>>>(x2_0, X2f, X2b[0], 8192*1024);
  k_state_init<<<G(8192*256),  blk, 0, stream>>>(x3_0, X3f, X3b[0], 8192*256);
  k_transpose_scale<<<G(256*1024),  blk, 0, stream>>>(W2, W2t, 256, 1024, 1.0f);
  k_transpose_scale<<<G(1024*256),  blk, 0, stream>>>(W3, W3t, 1024, 256, 1.0f);
  k_transpose_scale<<<G(256*256),   blk, 0, stream>>>(L1, L1t, 256, 256, -0.1f);
  k_transpose_scale<<<G(1024*1024), blk, 0, stream>>>(L2, L2t, 1024, 1024, -0.1f);
  k_conv_bf<<<G(256*1024), blk, 0, stream>>>(W2, W2b, 256*1024);
  k_conv_bf<<<G(1024*256), blk, 0, stream>>>(W3, W3b, 1024*256);
  k_m4g<<<G(256*256), blk, 0, stream>>>(W4, L3, M4G);
  k_xsplit<<<G(8192*1600), blk, 0, stream>>>(x, XS);
  k_w1c<<<G(256*1600), blk, 0, stream>>>(W1, W1c);

  auto mkg = [](const u16* A, const u16* Bt, int lda, int ldb, int K, int N,
                int tnl, int nb, int epi) {
    GemmDesc g; memset(&g, 0, sizeof(g));
    g.A = A; g.Bt = Bt; g.lda = lda; g.ldb = ldb; g.K = K; g.N = N;
    g.tnl = tnl; g.nblocks = nb; g.epi = epi;
    return g;
  };

  {  // x1_pred = sigmoid(x @ W1 + b1), via hi/lo K-concat (K=1600)
    Descs pp; memset(&pp, 0, sizeof(pp)); pp.nd = 1;
    pp.d[0] = mkg(XS, W1c, 1600, 1600, 1600, 256, 1, 128, 2);
    pp.d[0].bias = b1; pp.d[0].outF = P1;
    k_gemm_multi<<<dim3(128), blk, 0, stream>>>(pp);
  }
  // C4 AFTER x1_pred gemm (C4 aliases XS region)
  k_c4<<<G(8192*256), blk, 0, stream>>>(W4, b4, x4_0, C4);

  for (int s = 0; s < 20; ++s) {
    int p = s & 1, q = p ^ 1;

    // ---- phase 1: e3 (K=1024), e2 -- epilogues read bf16 shadows ----
    Descs ph1; memset(&ph1, 0, sizeof(ph1)); ph1.nd = 2;
    ph1.d[0] = mkg(X2b[p], W3t, 1024, 1024, 1024, 256, 1, 128, 1);
    ph1.d[0].bias = b3; ph1.d[0].eprev = X3b[p]; ph1.d[0].outB = E3;
    ph1.d[1] = mkg(X1b[p], W2t, 256, 256, 256, 1024, 3, 512, 1);
    ph1.d[1].bias = b2; ph1.d[1].eprev = X2b[p]; ph1.d[1].outB = E2;
    k_gemm_multi<<<dim3(640), blk, 0, stream>>>(ph1);

    // ---- phase 2: fused updates ----
    Descs ph2; memset(&ph2, 0, sizeof(ph2)); ph2.nd = 3;
    // x2: acc = E3@W3b (K=256) + X2b@L2t (K=1024)
    ph2.d[0] = mkg(E3, W3b, 256, 256, 256, 1024, 3, 512, 4);
    ph2.d[0].A2 = X2b[p]; ph2.d[0].Bt2 = L2t; ph2.d[0].lda2 = 1024;
    ph2.d[0].ldb2 = 1024; ph2.d[0].K2 = 1024;
    ph2.d[0].eprev = E2; ph2.d[0].outF = X2f; ph2.d[0].outB = X2b[q];
    // x1: acc = E2@W2b (K=1024) + X1b@L1t (K=256)
    ph2.d[1] = mkg(E2, W2b, 1024, 1024, 1024, 256, 1, 128, 3);
    ph2.d[1].A2 = X1b[p]; ph2.d[1].Bt2 = L1t; ph2.d[1].lda2 = 256;
    ph2.d[1].ldb2 = 256; ph2.d[1].K2 = 256;
    ph2.d[1].pred = P1; ph2.d[1].outF = X1f; ph2.d[1].outB = X1b[q];
    // x3: acc = X3b@(W4W4^T - gamma*L3) (K=256), + C4 const in epilogue
    ph2.d[2] = mkg(X3b[p], M4G, 256, 256, 256, 256, 1, 128, 6);
    ph2.d[2].eprev = E3; ph2.d[2].pred = C4;
    ph2.d[2].outF = X3f; ph2.d[2].outB = X3b[q];
    k_gemm_multi<<<dim3(768), blk, 0, stream>>>(ph2);
  }

  k_final<<<G(81920), blk, 0, stream>>>(X3f, W4, b4, (float*)d_out);
}